// Round 5
// baseline (145.493 us; speedup 1.0000x reference)
//
#include <hip/hip_runtime.h>
#include <math.h>

#define D_DIM 100000
#define W_DIM 128
#define BATCH 4096
#define BPAD  7168   // 7 * 1024 padded bucket counters; buckets = idx>>4 (6250 used)

// ---------------------------------------------------------------------------
// Kernel A: counting sort of (idx, b) by cache line (idx>>4). One block per
// matrix (2 blocks, 1024 threads). Hierarchical shuffle scan (5 barriers).
// Outputs: sidx[m][pos] = idx value at sorted position pos (ascending lines)
//          inv[m][b]    = sorted position of batch element b
// ---------------------------------------------------------------------------
__global__ __launch_bounds__(1024) void bucket_sort(
    const int* __restrict__ idx1, const int* __restrict__ idx2,
    int* __restrict__ sidx, int* __restrict__ inv)
{
    __shared__ int cnt[BPAD];     // 28 KB
    __shared__ int ranks[BATCH];  // 16 KB
    __shared__ int wsum[16];

    const int m = blockIdx.x;
    const int* __restrict__ idx = m ? idx2 : idx1;
    const int t    = threadIdx.x;
    const int lane = t & 63;
    const int wv   = t >> 6;

    for (int i = t; i < BPAD; i += 1024) cnt[i] = 0;
    __syncthreads();

    #pragma unroll
    for (int j = 0; j < 4; ++j) {
        const int i = t + j * 1024;
        ranks[i] = atomicAdd(&cnt[idx[i] >> 4], 1);
    }
    __syncthreads();

    // Per-thread total over its 7 buckets, then hierarchical shuffle scan.
    const int base = t * 7;
    int c[7]; int s = 0;
    #pragma unroll
    for (int j = 0; j < 7; ++j) { c[j] = cnt[base + j]; s += c[j]; }

    int inc = s;
    #pragma unroll
    for (int off = 1; off < 64; off <<= 1) {
        const int v = __shfl_up(inc, off, 64);
        if (lane >= off) inc += v;
    }
    if (lane == 63) wsum[wv] = inc;
    __syncthreads();

    if (t < 16) {
        const int v = wsum[t];
        int winc = v;
        #pragma unroll
        for (int off = 1; off < 16; off <<= 1) {
            const int u = __shfl_up(winc, off, 16);
            if (t >= off) winc += u;
        }
        wsum[t] = winc - v;   // exclusive wave offset
    }
    __syncthreads();

    int excl = wsum[wv] + (inc - s);   // exclusive thread offset
    #pragma unroll
    for (int j = 0; j < 7; ++j) { cnt[base + j] = excl; excl += c[j]; }
    __syncthreads();

    #pragma unroll
    for (int j = 0; j < 4; ++j) {
        const int i = t + j * 1024;
        const int v = idx[i];
        const int pos = cnt[v >> 4] + ranks[i];
        sidx[(m << 12) + pos] = v;
        inv [(m << 12) + i]   = pos;
    }
}

// ---------------------------------------------------------------------------
// Kernel B: row-stream gather. Wave = one (m, w, 128-pos chunk); lane l
// handles sorted positions base+2l, base+2l+1. The 64 lanes' addresses are
// ASCENDING within a ~12 KB window of row w -> the coalescer merges
// same-line duplicates in-flight and DRAM gets dense ascending bursts.
// Writes Ps[m][w][pos] as coalesced float2.
// 8192 waves -> 2048 blocks x 256.
// ---------------------------------------------------------------------------
__global__ __launch_bounds__(256) void gather(
    const int* __restrict__ sidx,
    const float* __restrict__ W1, const float* __restrict__ b1,
    const float* __restrict__ W2, const float* __restrict__ b2,
    float* __restrict__ Ps)   // [2][128][4096]
{
    const int g  = (blockIdx.x << 2) + (threadIdx.x >> 6);  // wave id [0,8192)
    const int l  = threadIdx.x & 63;
    const int m  = g >> 12;
    const int rem = g & 4095;        // w*32 + chunk
    const int w   = rem >> 5;
    const int p0  = ((rem & 31) << 7) + (l << 1);  // sorted position (pair)

    const int2 ii = *(const int2*)&sidx[(m << 12) + p0];

    const float* __restrict__ row = (m ? W2 : W1) + (size_t)w * D_DIM;
    const float bias = m ? b2[w] : b1[w];

    const float v0 = row[ii.x] + bias;
    const float v1 = row[ii.y] + bias;

    float2* dst = (float2*)&Ps[(((size_t)(m << 7) + w) << 12) + p0];
    *dst = make_float2(v0, v1);
}

// ---------------------------------------------------------------------------
// Kernel C: permutation-join dot. Lane = b; wave wv covers 32 w's; LDS
// reduce. Ps is 4 MB, L2/L3-hot right after kernel B. 64 blocks x 256.
// ---------------------------------------------------------------------------
__global__ __launch_bounds__(256) void dot_sig(
    const float* __restrict__ Ps, const int* __restrict__ inv,
    float* __restrict__ out)
{
    __shared__ float red[4][64];
    const int wv = threadIdx.x >> 6;
    const int l  = threadIdx.x & 63;
    const int b  = (blockIdx.x << 6) + l;

    const int p1 = inv[b];
    const int p2 = inv[BATCH + b];
    const float* __restrict__ P1 = Ps;
    const float* __restrict__ P2 = Ps + ((size_t)W_DIM << 12);

    float acc = 0.0f;
    #pragma unroll
    for (int k = 0; k < 32; ++k) {
        const int w = (wv << 5) + k;
        acc += P1[((size_t)w << 12) + p1] * P2[((size_t)w << 12) + p2];
    }
    red[wv][l] = acc;
    __syncthreads();

    if (wv == 0) {
        const float v = red[0][l] + red[1][l] + red[2][l] + red[3][l];
        const float s = 1.0f / (1.0f + expf(-v));
        ((float2*)out)[b] = make_float2(1.0f - s, s);
    }
}

extern "C" void kernel_launch(void* const* d_in, const int* in_sizes, int n_in,
                              void* d_out, int out_size, void* d_ws, size_t ws_size,
                              hipStream_t stream)
{
    const int*   idx1 = (const int*)  d_in[0];
    const int*   idx2 = (const int*)  d_in[1];
    const float* W1   = (const float*)d_in[2];
    const float* b1   = (const float*)d_in[3];
    const float* W2   = (const float*)d_in[4];
    const float* b2   = (const float*)d_in[5];
    float* out = (float*)d_out;

    int* sidx = (int*)d_ws;                               // 32 KB
    int* inv  = sidx + 2 * BATCH;                         // 32 KB
    float* Ps = (float*)((char*)d_ws + 65536);            // 4 MB

    bucket_sort<<<2, 1024, 0, stream>>>(idx1, idx2, sidx, inv);
    gather<<<2048, 256, 0, stream>>>(sidx, W1, b1, W2, b2, Ps);
    dot_sig<<<BATCH / 64, 256, 0, stream>>>(Ps, inv, out);
}

// Round 6
// 136.356 us; speedup vs baseline: 1.0670x; 1.0670x over previous
//
#include <hip/hip_runtime.h>
#include <math.h>

#define D_DIM 100000
#define W_DIM 128
#define BATCH 4096
#define BPAD  7168   // 7 * 1024 padded bucket counters; buckets = idx>>4 (6250 used)

// ---------------------------------------------------------------------------
// Kernel A: counting sort of (idx, b) by cache line (idx>>4). One block per
// matrix (2 blocks, 1024 threads). Hierarchical shuffle scan (5 barriers).
// Outputs: sidx[m][pos] = idx value at sorted position pos (ascending lines)
//          inv[m][b]    = sorted position of batch element b
// ---------------------------------------------------------------------------
__global__ __launch_bounds__(1024) void bucket_sort(
    const int* __restrict__ idx1, const int* __restrict__ idx2,
    int* __restrict__ sidx, int* __restrict__ inv)
{
    __shared__ int cnt[BPAD];     // 28 KB
    __shared__ int ranks[BATCH];  // 16 KB
    __shared__ int wsum[16];

    const int m = blockIdx.x;
    const int* __restrict__ idx = m ? idx2 : idx1;
    const int t    = threadIdx.x;
    const int lane = t & 63;
    const int wv   = t >> 6;

    for (int i = t; i < BPAD; i += 1024) cnt[i] = 0;
    __syncthreads();

    #pragma unroll
    for (int j = 0; j < 4; ++j) {
        const int i = t + j * 1024;
        ranks[i] = atomicAdd(&cnt[idx[i] >> 4], 1);
    }
    __syncthreads();

    const int base = t * 7;
    int c[7]; int s = 0;
    #pragma unroll
    for (int j = 0; j < 7; ++j) { c[j] = cnt[base + j]; s += c[j]; }

    int inc = s;
    #pragma unroll
    for (int off = 1; off < 64; off <<= 1) {
        const int v = __shfl_up(inc, off, 64);
        if (lane >= off) inc += v;
    }
    if (lane == 63) wsum[wv] = inc;
    __syncthreads();

    if (t < 16) {
        const int v = wsum[t];
        int winc = v;
        #pragma unroll
        for (int off = 1; off < 16; off <<= 1) {
            const int u = __shfl_up(winc, off, 16);
            if (t >= off) winc += u;
        }
        wsum[t] = winc - v;   // exclusive wave offset
    }
    __syncthreads();

    int excl = wsum[wv] + (inc - s);   // exclusive thread offset
    #pragma unroll
    for (int j = 0; j < 7; ++j) { cnt[base + j] = excl; excl += c[j]; }
    __syncthreads();

    #pragma unroll
    for (int j = 0; j < 4; ++j) {
        const int i = t + j * 1024;
        const int v = idx[i];
        const int pos = cnt[v >> 4] + ranks[i];
        sidx[(m << 12) + pos] = v;
        inv [(m << 12) + i]   = pos;
    }
}

// ---------------------------------------------------------------------------
// Kernel B: windowed sorted gather. 1024 waves (256 blocks): wave =
// (m, w, quarter). Each wave walks 1024 CONSECUTIVE sorted positions in 8
// unrolled iterations: lanes read ascending addresses within a ~12 KB window
// of row w -> DRAM row-buffer hits; concurrency is 1024 narrow ascending
// streams instead of a grid-wide 100 MB scatter. Writes Ps[m][w][pos]
// coalesced float2.
// ---------------------------------------------------------------------------
__global__ __launch_bounds__(256) void gather(
    const int* __restrict__ sidx,
    const float* __restrict__ W1, const float* __restrict__ b1,
    const float* __restrict__ W2, const float* __restrict__ b2,
    float* __restrict__ Ps)   // [2][128][4096]
{
    const int g = (blockIdx.x << 2) + (threadIdx.x >> 6);  // wave id [0,1024)
    const int l = threadIdx.x & 63;
    const int m = g >> 9;
    const int w = (g >> 2) & 127;
    const int q = g & 3;

    const float* __restrict__ row = (m ? W2 : W1) + (size_t)w * D_DIM;
    const float bias = m ? b2[w] : b1[w];

    const int pbase = (q << 10) + (l << 1);
    const int* __restrict__ sp = sidx + (m << 12);
    float* __restrict__ dst = Ps + (((size_t)(m << 7) + w) << 12);

    #pragma unroll
    for (int it = 0; it < 8; ++it) {
        const int p = pbase + (it << 7);
        const int2 ii = *(const int2*)&sp[p];
        const float v0 = row[ii.x] + bias;
        const float v1 = row[ii.y] + bias;
        *(float2*)&dst[p] = make_float2(v0, v1);
    }
}

// ---------------------------------------------------------------------------
// Kernel C: permutation-join dot, high-parallelism version. 256 blocks x 256
// threads; 16 threads per batch element, 8 w's each (16 scattered L2/L3
// reads per thread, all independent), segment shuffle reduce, sigmoid.
// ---------------------------------------------------------------------------
__global__ __launch_bounds__(256) void dot_sig(
    const float* __restrict__ Ps, const int* __restrict__ inv,
    float* __restrict__ out)
{
    const int t   = (blockIdx.x << 8) + threadIdx.x;  // [0, 65536)
    const int b   = t >> 4;
    const int seg = t & 15;

    const int p1 = inv[b];
    const int p2 = inv[BATCH + b];
    const float* __restrict__ P1 = Ps;
    const float* __restrict__ P2 = Ps + ((size_t)W_DIM << 12);

    float acc = 0.0f;
    #pragma unroll
    for (int k = 0; k < 8; ++k) {
        const int w = (seg << 3) + k;
        acc += P1[((size_t)w << 12) + p1] * P2[((size_t)w << 12) + p2];
    }
    acc += __shfl_down(acc, 8, 16);
    acc += __shfl_down(acc, 4, 16);
    acc += __shfl_down(acc, 2, 16);
    acc += __shfl_down(acc, 1, 16);

    if (seg == 0) {
        const float s = 1.0f / (1.0f + expf(-acc));
        ((float2*)out)[b] = make_float2(1.0f - s, s);
    }
}

extern "C" void kernel_launch(void* const* d_in, const int* in_sizes, int n_in,
                              void* d_out, int out_size, void* d_ws, size_t ws_size,
                              hipStream_t stream)
{
    const int*   idx1 = (const int*)  d_in[0];
    const int*   idx2 = (const int*)  d_in[1];
    const float* W1   = (const float*)d_in[2];
    const float* b1   = (const float*)d_in[3];
    const float* W2   = (const float*)d_in[4];
    const float* b2   = (const float*)d_in[5];
    float* out = (float*)d_out;

    int* sidx = (int*)d_ws;                               // 32 KB
    int* inv  = sidx + 2 * BATCH;                         // 32 KB
    float* Ps = (float*)((char*)d_ws + 65536);            // 4 MB

    bucket_sort<<<2, 1024, 0, stream>>>(idx1, idx2, sidx, inv);
    gather<<<256, 256, 0, stream>>>(sidx, W1, b1, W2, b2, Ps);
    dot_sig<<<256, 256, 0, stream>>>(Ps, inv, out);
}